// Round 2
// baseline (3093.131 us; speedup 1.0000x reference)
//
#include <hip/hip_runtime.h>
#include <hip/hip_bf16.h>
#include <math.h>

#define BB 32
#define SS 512
#define DD 256
#define HH 8
#define HDIM 32
#define FFNN 128
#define NROWS (BB*SS)        // 16384
#define NELEM (NROWS*DD)     // 4194304

using bf16 = __hip_bfloat16;
static __device__ __forceinline__ float bf2f(bf16 x) { return __bfloat162float(x); }
static __device__ __forceinline__ bf16  f2bf(float x) { return __float2bfloat16(x); }

// ---------- v dtype probe: int64 buffers have all odd int32 words == 0 ----------
__global__ void init_flag(int* flag) { *flag = 0; }
__global__ __launch_bounds__(256) void detect_v(const int* __restrict__ v, int* __restrict__ flag) {
    int i = blockIdx.x * 256 + threadIdx.x;     // 0..8191
    if (v[2 * i + 1] != 0) atomicOr(flag, 1);   // any nonzero odd word -> int32 layout
}

// ---------- embed: X = relu(emb[v]), emb row 0 forced to 0 ----------
__global__ __launch_bounds__(256) void embed_kernel(const int* __restrict__ v,
                                                    const float* __restrict__ emb,
                                                    const int* __restrict__ flag,
                                                    float* __restrict__ X) {
    int idx = blockIdx.x * 256 + threadIdx.x;
    int d = idx & (DD - 1);
    int row = idx >> 8;
    int tok = (*flag) ? v[row] : v[2 * row];    // int32 vs int64 layout
    float val = 0.0f;
    if (tok != 0) {
        val = emb[tok * DD + d];
        val = val > 0.0f ? val : 0.0f;
    }
    X[idx] = val;
}

// ---------- per-row layernorm stats: stats[2r]=mu, stats[2r+1]=rstd ----------
__global__ __launch_bounds__(256) void ln_stats_kernel(const float* __restrict__ X,
                                                       float* __restrict__ stats) {
    int row = blockIdx.x;
    float x = X[(size_t)row * DD + threadIdx.x];
    float s1 = x, s2 = x * x;
    #pragma unroll
    for (int off = 1; off < 64; off <<= 1) {
        s1 += __shfl_xor(s1, off);
        s2 += __shfl_xor(s2, off);
    }
    __shared__ float p1[4], p2[4];
    int wid = threadIdx.x >> 6;
    if ((threadIdx.x & 63) == 0) { p1[wid] = s1; p2[wid] = s2; }
    __syncthreads();
    if (threadIdx.x == 0) {
        float t1 = p1[0] + p1[1] + p1[2] + p1[3];
        float t2 = p2[0] + p2[1] + p2[2] + p2[3];
        float mu = t1 * (1.0f / DD);
        float var = t2 * (1.0f / DD) - mu * mu;
        stats[2 * row] = mu;
        stats[2 * row + 1] = rsqrtf(var + 1e-5f);
    }
}

// ---------- fused Q|K|V|G GEMM (N=1024), LN1 applied on the fly, xPos in epilogue ----------
// out layout: QKVG[row][0:256]=Q(rot,up) [256:512]=K(rot,down) [512:768]=V [768:1024]=G, bf16
__global__ __launch_bounds__(256) void qkvg_kernel(const float* __restrict__ X,
                                                   const float* __restrict__ stats,
                                                   const float* __restrict__ lnw,
                                                   const float* __restrict__ lnb,
                                                   const float* __restrict__ WQ,
                                                   const float* __restrict__ WK,
                                                   const float* __restrict__ WV,
                                                   const float* __restrict__ WG,
                                                   bf16* __restrict__ QKVG) {
    __shared__ float As[32][33];
    __shared__ float Bs[32][33];
    int tx = threadIdx.x, ty = threadIdx.y;
    int tid = ty * 16 + tx;
    int col0 = blockIdx.x * 32;          // 0..1023
    int row0 = blockIdx.y * 32;
    int seg = col0 >> 8;                 // 0=Q 1=K 2=V 3=G
    const float* Wp = (seg == 0) ? WQ : (seg == 1) ? WK : (seg == 2) ? WV : WG;
    float acc00 = 0.f, acc01 = 0.f, acc10 = 0.f, acc11 = 0.f;

    for (int k0 = 0; k0 < DD; k0 += 32) {
        #pragma unroll
        for (int i = tid; i < 32 * 32; i += 256) {
            int r = i >> 5, c = i & 31;
            int row = row0 + r;
            int k = k0 + c;
            float x = X[(size_t)row * DD + k];
            As[r][c] = (x - stats[2 * row]) * stats[2 * row + 1] * lnw[k] + lnb[k];
            int j = (col0 & 255) + c;    // column within segment
            int bk = k0 + r;
            float wv;
            if (seg < 3) {               // (H, D, HD) layout
                wv = Wp[((j >> 5) * DD + bk) * HDIM + (j & 31)];
            } else {                     // (D, D) layout
                wv = Wp[(size_t)bk * DD + j];
            }
            Bs[r][c] = wv;
        }
        __syncthreads();
        #pragma unroll
        for (int k = 0; k < 32; ++k) {
            float a0 = As[2 * ty][k], a1 = As[2 * ty + 1][k];
            float b0 = Bs[k][2 * tx], b1 = Bs[k][2 * tx + 1];
            acc00 += a0 * b0; acc01 += a0 * b1;
            acc10 += a1 * b0; acc11 += a1 * b1;
        }
        __syncthreads();
    }

    int c = col0 + 2 * tx;               // even global column
    float vals[2][2] = {{acc00, acc01}, {acc10, acc11}};
    if (seg < 2) {                       // xPos rotary: pair (c, c+1), freq jf
        int jf = (c & 31) >> 1;          // 0..15
        float base = (2.0f * jf + 0.4f * HDIM) / (1.4f * HDIM);
        float inv_freq = powf(10000.0f, -(float)jf / 16.0f);
        #pragma unroll
        for (int ii = 0; ii < 2; ++ii) {
            int r = row0 + 2 * ty + ii;
            float s = (float)(r & (SS - 1));
            float sm = powf(base, s * (1.0f / 512.0f));
            if (seg == 1) sm = 1.0f / sm;
            float sn, cs;
            sincosf(s * inv_freq, &sn, &cs);
            float v0 = vals[ii][0], v1 = vals[ii][1];
            vals[ii][0] = (v0 * cs - v1 * sn) * sm;
            vals[ii][1] = (v1 * cs + v0 * sn) * sm;
        }
    }
    #pragma unroll
    for (int ii = 0; ii < 2; ++ii) {
        int r = row0 + 2 * ty + ii;
        QKVG[(size_t)r * 1024 + c]     = f2bf(vals[ii][0]);
        QKVG[(size_t)r * 1024 + c + 1] = f2bf(vals[ii][1]);
    }
}

// ---------- retention + groupnorm(32) + silu(G) gate; writes T over the Q slot ----------
__global__ __launch_bounds__(64) void retention_kernel(bf16* __restrict__ QKVG,
                                                       const float* __restrict__ gnw,
                                                       const float* __restrict__ gnb) {
    int s = blockIdx.x;
    int bh = blockIdx.y;
    int b = bh >> 3, h = bh & 7;
    int lane = threadIdx.x;
    size_t rowbase = (size_t)(b * SS + s) * 1024;
    __shared__ float qs[HDIM];
    __shared__ float wbuf[64];
    if (lane < HDIM) qs[lane] = bf2f(QKVG[rowbase + h * HDIM + lane]);
    __syncthreads();
    const float a0 = -3.46573590280f;    // ln(1/32)
    const float a1 = -6.23832462504f;    // ln(1/512)
    float gamma = 1.0f - expf(a0 + (float)h * (a1 - a0) / 7.0f);
    float lg = logf(gamma);
    float acc = 0.0f;                    // lanes<32: Y[b,s,h,lane]
    for (int tb = 0; tb <= s; tb += 64) {
        int t = tb + lane;
        float w = 0.0f;
        if (t <= s) {
            const bf16* Krow = QKVG + (size_t)(b * SS + t) * 1024 + 256 + h * HDIM;
            float dot = 0.0f;
            #pragma unroll
            for (int e = 0; e < HDIM; ++e) dot += qs[e] * bf2f(Krow[e]);
            w = dot * expf((float)(s - t) * lg);
        }
        wbuf[lane] = w;
        __syncthreads();
        if (lane < HDIM) {
            int tmax = min(64, s - tb + 1);
            const bf16* Vb = QKVG + (size_t)(b * SS + tb) * 1024 + 512 + h * HDIM + lane;
            for (int l = 0; l < tmax; ++l)
                acc += wbuf[l] * bf2f(Vb[(size_t)l * 1024]);
        }
        __syncthreads();
    }
    if (lane < HDIM) {
        float s1 = acc, s2 = acc * acc;
        #pragma unroll
        for (int off = 1; off < 32; off <<= 1) {
            s1 += __shfl_xor(s1, off);
            s2 += __shfl_xor(s2, off);
        }
        float mu = s1 * (1.0f / HDIM);
        float var = s2 * (1.0f / HDIM) - mu * mu;
        int d = h * HDIM + lane;
        float yn = (acc - mu) * rsqrtf(var + 1e-5f) * gnw[d] + gnb[d];
        float g = bf2f(QKVG[rowbase + 768 + d]);
        float t = g / (1.0f + expf(-g)) * yn;   // silu(g)*yn
        QKVG[rowbase + d] = f2bf(t);            // T into Q slot
    }
}

// ---------- generic tiled GEMM: C = act(Aeff @ W + bias) + addsrc ----------
template<bool ABF16, bool ALN, bool GELU, bool CBF16, bool BIAS, bool ADD>
__global__ __launch_bounds__(256) void gemm_t(const void* __restrict__ Av, int lda,
                                              const float* __restrict__ stats,
                                              const float* __restrict__ lnw,
                                              const float* __restrict__ lnb,
                                              const float* __restrict__ W,
                                              const float* __restrict__ bias,
                                              const float* __restrict__ addsrc, int ldadd,
                                              void* __restrict__ Cv, int ldc,
                                              int N, int K) {
    __shared__ float As[32][33];
    __shared__ float Bs[32][33];
    int tx = threadIdx.x, ty = threadIdx.y;
    int tid = ty * 16 + tx;
    int col0 = blockIdx.x * 32;
    int row0 = blockIdx.y * 32;
    float acc00 = 0.f, acc01 = 0.f, acc10 = 0.f, acc11 = 0.f;

    for (int k0 = 0; k0 < K; k0 += 32) {
        #pragma unroll
        for (int i = tid; i < 32 * 32; i += 256) {
            int r = i >> 5, c = i & 31;
            int row = row0 + r;
            int k = k0 + c;
            float a;
            if (ABF16) a = bf2f(((const bf16*)Av)[(size_t)row * lda + k]);
            else       a = ((const float*)Av)[(size_t)row * lda + k];
            if (ALN)   a = (a - stats[2 * row]) * stats[2 * row + 1] * lnw[k] + lnb[k];
            As[r][c] = a;
            Bs[r][c] = W[(size_t)(k0 + r) * N + col0 + c];
        }
        __syncthreads();
        #pragma unroll
        for (int k = 0; k < 32; ++k) {
            float a0 = As[2 * ty][k], a1 = As[2 * ty + 1][k];
            float b0 = Bs[k][2 * tx], b1 = Bs[k][2 * tx + 1];
            acc00 += a0 * b0; acc01 += a0 * b1;
            acc10 += a1 * b0; acc11 += a1 * b1;
        }
        __syncthreads();
    }

    float vals[2][2] = {{acc00, acc01}, {acc10, acc11}};
    #pragma unroll
    for (int ii = 0; ii < 2; ++ii) {
        #pragma unroll
        for (int jj = 0; jj < 2; ++jj) {
            int r = row0 + 2 * ty + ii;
            int c = col0 + 2 * tx + jj;
            float v = vals[ii][jj];
            if (BIAS) v += bias[c];
            if (GELU) v = 0.5f * v * (1.0f + erff(v * 0.70710678118f));
            if (ADD)  v += addsrc[(size_t)r * ldadd + c];
            if (CBF16) ((bf16*)Cv)[(size_t)r * ldc + c] = f2bf(v);
            else       ((float*)Cv)[(size_t)r * ldc + c] = v;
        }
    }
}

// ---------- final copy (f32 out) ----------
__global__ __launch_bounds__(256) void copy_kernel(const float* __restrict__ X,
                                                   float* __restrict__ out) {
    int idx = blockIdx.x * 256 + threadIdx.x;
    out[idx] = X[idx];
}

extern "C" void kernel_launch(void* const* d_in, const int* in_sizes, int n_in,
                              void* d_out, int out_size, void* d_ws, size_t ws_size,
                              hipStream_t stream) {
    const int*   v    = (const int*)d_in[0];
    const float* emb  = (const float*)d_in[1];
    const float* WQ   = (const float*)d_in[2];
    const float* WK   = (const float*)d_in[3];
    const float* WV   = (const float*)d_in[4];
    const float* WG   = (const float*)d_in[5];
    const float* WO   = (const float*)d_in[6];
    const float* gn_w = (const float*)d_in[7];
    const float* gn_b = (const float*)d_in[8];
    const float* ln1w = (const float*)d_in[9];
    const float* ln1b = (const float*)d_in[10];
    const float* ln2w = (const float*)d_in[11];
    const float* ln2b = (const float*)d_in[12];
    const float* w1   = (const float*)d_in[13];
    const float* b1   = (const float*)d_in[14];
    const float* w2   = (const float*)d_in[15];
    const float* b2   = (const float*)d_in[16];
    float* out = (float*)d_out;

    // workspace layout (floats): [flag pad 16] [X 4194304] [stats 32768] [QKVG bf16 16M elems] [Hf bf16 2M elems]
    float* base  = (float*)d_ws;
    int*   flag  = (int*)base;
    float* X     = base + 16;
    float* stats = X + NELEM;
    bf16*  QKVG  = (bf16*)(stats + 2 * NROWS);
    bf16*  Hf    = QKVG + (size_t)NROWS * 1024;

    dim3 blk(16, 16);

    init_flag<<<1, 1, 0, stream>>>(flag);
    detect_v<<<32, 256, 0, stream>>>(v, flag);
    embed_kernel<<<NELEM / 256, 256, 0, stream>>>(v, emb, flag, X);

    for (int i = 0; i < 3; ++i) {
        const float* WQi = WQ + (size_t)i * HH * DD * HDIM;
        const float* WKi = WK + (size_t)i * HH * DD * HDIM;
        const float* WVi = WV + (size_t)i * HH * DD * HDIM;
        const float* WGi = WG + (size_t)i * DD * DD;
        const float* WOi = WO + (size_t)i * DD * DD;
        const float* w1i = w1 + (size_t)i * DD * FFNN;
        const float* w2i = w2 + (size_t)i * FFNN * DD;

        // LN1 stats, fused QKVG gemm (+xPos), retention(+gn+gate)
        ln_stats_kernel<<<NROWS, 256, 0, stream>>>(X, stats);
        qkvg_kernel<<<dim3(32, NROWS / 32), blk, 0, stream>>>(X, stats, ln1w + i * DD, ln1b + i * DD,
                                                              WQi, WKi, WVi, WGi, QKVG);
        retention_kernel<<<dim3(SS, BB * HH), 64, 0, stream>>>(QKVG, gn_w + i * DD, gn_b + i * DD);
        // Y = T @ WO + X  (in-place over X)
        gemm_t<true, false, false, false, false, true>
            <<<dim3(8, NROWS / 32), blk, 0, stream>>>(QKVG, 1024, nullptr, nullptr, nullptr,
                                                      WOi, nullptr, X, DD, X, DD, DD, DD);
        // LN2 stats, FFN1 (gelu, bf16 out), FFN2 (+bias +residual, in-place over X)
        ln_stats_kernel<<<NROWS, 256, 0, stream>>>(X, stats);
        gemm_t<false, true, true, true, true, false>
            <<<dim3(4, NROWS / 32), blk, 0, stream>>>(X, DD, stats, ln2w + i * DD, ln2b + i * DD,
                                                      w1i, b1 + i * FFNN, nullptr, 0, Hf, FFNN, FFNN, DD);
        gemm_t<true, false, false, false, true, true>
            <<<dim3(8, NROWS / 32), blk, 0, stream>>>(Hf, FFNN, nullptr, nullptr, nullptr,
                                                      w2i, b2 + i * DD, X, DD, X, DD, DD, FFNN);
    }

    copy_kernel<<<NELEM / 256, 256, 0, stream>>>(X, out);
}

// Round 4
// 1676.630 us; speedup vs baseline: 1.8449x; 1.8449x over previous
//
#include <hip/hip_runtime.h>
#include <hip/hip_bf16.h>
#include <math.h>

#define BB 32
#define SS 512
#define DD 256
#define HH 8
#define HDIM 32
#define FFNN 128
#define NROWS (BB*SS)        // 16384
#define NELEM (NROWS*DD)     // 4194304

using bf16 = __hip_bfloat16;
typedef __attribute__((ext_vector_type(8))) short short8;
typedef __attribute__((ext_vector_type(4))) float floatx4;

static __device__ __forceinline__ float bf2f(bf16 x) { return __bfloat162float(x); }
static __device__ __forceinline__ bf16  f2bf(float x) { return __float2bfloat16(x); }
static __device__ __forceinline__ short f2bfs(float x) {
    bf16 b = __float2bfloat16(x);
    return __builtin_bit_cast(short, b);
}

// ---------- v dtype probe: int64 buffers have all odd int32 words == 0 ----------
__global__ void init_flag(int* flag) { *flag = 0; }
__global__ __launch_bounds__(256) void detect_v(const int* __restrict__ v, int* __restrict__ flag) {
    int i = blockIdx.x * 256 + threadIdx.x;     // 0..8191
    if (v[2 * i + 1] != 0) atomicOr(flag, 1);   // any nonzero odd word -> int32 layout
}

// ---------- embed: X = relu(emb[v]), emb row 0 forced to 0 ----------
__global__ __launch_bounds__(256) void embed_kernel(const int* __restrict__ v,
                                                    const float* __restrict__ emb,
                                                    const int* __restrict__ flag,
                                                    float* __restrict__ X) {
    int idx = blockIdx.x * 256 + threadIdx.x;
    int d = idx & (DD - 1);
    int row = idx >> 8;
    int tok = (*flag) ? v[row] : v[2 * row];    // int32 vs int64 layout
    float val = 0.0f;
    if (tok != 0) {
        val = emb[tok * DD + d];
        val = val > 0.0f ? val : 0.0f;
    }
    X[idx] = val;
}

// ---------- per-row layernorm stats: stats[2r]=mu, stats[2r+1]=rstd ----------
__global__ __launch_bounds__(256) void ln_stats_kernel(const float* __restrict__ X,
                                                       float* __restrict__ stats) {
    int row = blockIdx.x;
    float x = X[(size_t)row * DD + threadIdx.x];
    float s1 = x, s2 = x * x;
    #pragma unroll
    for (int off = 1; off < 64; off <<= 1) {
        s1 += __shfl_xor(s1, off);
        s2 += __shfl_xor(s2, off);
    }
    __shared__ float p1[4], p2[4];
    int wid = threadIdx.x >> 6;
    if ((threadIdx.x & 63) == 0) { p1[wid] = s1; p2[wid] = s2; }
    __syncthreads();
    if (threadIdx.x == 0) {
        float t1 = p1[0] + p1[1] + p1[2] + p1[3];
        float t2 = p2[0] + p2[1] + p2[2] + p2[3];
        float mu = t1 * (1.0f / DD);
        float var = t2 * (1.0f / DD) - mu * mu;
        stats[2 * row] = mu;
        stats[2 * row + 1] = rsqrtf(var + 1e-5f);
    }
}

// ---------- fused Q|K|V|G GEMM (N=1024), LN1 applied on the fly, xPos in epilogue ----------
__global__ __launch_bounds__(256) void qkvg_kernel(const float* __restrict__ X,
                                                   const float* __restrict__ stats,
                                                   const float* __restrict__ lnw,
                                                   const float* __restrict__ lnb,
                                                   const float* __restrict__ WQ,
                                                   const float* __restrict__ WK,
                                                   const float* __restrict__ WV,
                                                   const float* __restrict__ WG,
                                                   bf16* __restrict__ QKVG) {
    __shared__ float As[32][33];
    __shared__ float Bs[32][33];
    int tx = threadIdx.x, ty = threadIdx.y;
    int tid = ty * 16 + tx;
    int col0 = blockIdx.x * 32;          // 0..1023
    int row0 = blockIdx.y * 32;
    int seg = col0 >> 8;                 // 0=Q 1=K 2=V 3=G
    const float* Wp = (seg == 0) ? WQ : (seg == 1) ? WK : (seg == 2) ? WV : WG;
    float acc00 = 0.f, acc01 = 0.f, acc10 = 0.f, acc11 = 0.f;

    for (int k0 = 0; k0 < DD; k0 += 32) {
        #pragma unroll
        for (int i = tid; i < 32 * 32; i += 256) {
            int r = i >> 5, c = i & 31;
            int row = row0 + r;
            int k = k0 + c;
            float x = X[(size_t)row * DD + k];
            As[r][c] = (x - stats[2 * row]) * stats[2 * row + 1] * lnw[k] + lnb[k];
            int j = (col0 & 255) + c;
            int bk = k0 + r;
            float wv;
            if (seg < 3) wv = Wp[((j >> 5) * DD + bk) * HDIM + (j & 31)];
            else         wv = Wp[(size_t)bk * DD + j];
            Bs[r][c] = wv;
        }
        __syncthreads();
        #pragma unroll
        for (int k = 0; k < 32; ++k) {
            float a0 = As[2 * ty][k], a1 = As[2 * ty + 1][k];
            float b0 = Bs[k][2 * tx], b1 = Bs[k][2 * tx + 1];
            acc00 += a0 * b0; acc01 += a0 * b1;
            acc10 += a1 * b0; acc11 += a1 * b1;
        }
        __syncthreads();
    }

    int c = col0 + 2 * tx;
    float vals[2][2] = {{acc00, acc01}, {acc10, acc11}};
    if (seg < 2) {
        int jf = (c & 31) >> 1;
        float base = (2.0f * jf + 0.4f * HDIM) / (1.4f * HDIM);
        float inv_freq = powf(10000.0f, -(float)jf / 16.0f);
        #pragma unroll
        for (int ii = 0; ii < 2; ++ii) {
            int r = row0 + 2 * ty + ii;
            float s = (float)(r & (SS - 1));
            float sm = powf(base, s * (1.0f / 512.0f));
            if (seg == 1) sm = 1.0f / sm;
            float sn, cs;
            sincosf(s * inv_freq, &sn, &cs);
            float v0 = vals[ii][0], v1 = vals[ii][1];
            vals[ii][0] = (v0 * cs - v1 * sn) * sm;
            vals[ii][1] = (v1 * cs + v0 * sn) * sm;
        }
    }
    #pragma unroll
    for (int ii = 0; ii < 2; ++ii) {
        int r = row0 + 2 * ty + ii;
        QKVG[(size_t)r * 1024 + c]     = f2bf(vals[ii][0]);
        QKVG[(size_t)r * 1024 + c + 1] = f2bf(vals[ii][1]);
    }
}

// ---------- MFMA retention + groupnorm(32) + silu(G) gate; writes T over the Q slot ----------
// block = 4 waves sharing one q-tile index qi (same trip count -> __syncthreads legal).
// wave w handles bh = (blockIdx&63)*4 + w. 16x16x32 bf16 MFMA; layouts per m89/m120:
//   A: A[m=lane&15][k=quad*8+j]  B: B[k=quad*8+j][n=lane&15]  C/D: col=lane&15, row=quad*4+reg
#define VSTRIDE 42
__global__ __launch_bounds__(256) void retention_mfma_kernel(bf16* __restrict__ QKVG,
                                                             const float* __restrict__ gnw,
                                                             const float* __restrict__ gnb) {
    __shared__ __align__(16) short Vl[4][32 * VSTRIDE];   // per-wave V tile [t][d]
    __shared__ __align__(16) short Pl[4][16 * 40];        // per-wave P tile [q][t]
    int wslot = threadIdx.x >> 6;
    int lane = threadIdx.x & 63;
    int qi = blockIdx.x >> 6;                     // 0..31 (shared by all 4 waves)
    int bh = ((blockIdx.x & 63) << 2) | wslot;    // 0..255
    int b = bh >> 3, h = bh & 7;
    int q0 = qi * 16;
    int lo = lane & 15, quad = lane >> 4;

    const float la0 = -3.46573590280f, la1 = -6.23832462504f;
    float gamma = 1.0f - expf(la0 + (float)h * (la1 - la0) / 7.0f);
    float lg2 = log2f(gamma);

    const size_t base = (size_t)b * SS * 1024;
    const short* QKVGs = (const short*)QKVG;

    // Q A-frag: Q[q0+lo][quad*8 + j]
    short8 qfrag = *(const short8*)(QKVGs + base + (size_t)(q0 + lo) * 1024 + h * HDIM + quad * 8);

    floatx4 o0 = {0.f, 0.f, 0.f, 0.f}, o1 = {0.f, 0.f, 0.f, 0.f};
    short* Vw = Vl[wslot];
    short* Pw = Pl[wslot];
    int nch = (qi >> 1) + 1;

    for (int ch = 0; ch < nch; ++ch) {
        int t0 = ch * 32;
        // K B-frags (direct from global, contiguous 16B per lane): B[k=d][n=t] = K[t][d]
        const short* Kb = QKVGs + base + 256 + h * HDIM + quad * 8;
        short8 kf0 = *(const short8*)(Kb + (size_t)(t0 + lo) * 1024);
        short8 kf1 = *(const short8*)(Kb + (size_t)(t0 + 16 + lo) * 1024);
        // stage V chunk [32t x 32d] into LDS
        {
            int r = lane >> 2, d = (lane & 3) * 8;
            const uint* Vg1 = (const uint*)(QKVGs + base + (size_t)(t0 + r) * 1024 + 512 + h * HDIM + d);
            const uint* Vg2 = (const uint*)(QKVGs + base + (size_t)(t0 + 16 + r) * 1024 + 512 + h * HDIM + d);
            uint* L1 = (uint*)(Vw + r * VSTRIDE + d);
            uint* L2 = (uint*)(Vw + (16 + r) * VSTRIDE + d);
            #pragma unroll
            for (int w = 0; w < 4; ++w) { L1[w] = Vg1[w]; L2[w] = Vg2[w]; }
        }
        // QK^T
        floatx4 z = {0.f, 0.f, 0.f, 0.f};
        floatx4 s0 = __builtin_amdgcn_mfma_f32_16x16x32_bf16(qfrag, kf0, z, 0, 0, 0);
        floatx4 s1 = __builtin_amdgcn_mfma_f32_16x16x32_bf16(qfrag, kf1, z, 0, 0, 0);
        // decay + causal mask -> P (bf16) into LDS
        #pragma unroll
        for (int r = 0; r < 4; ++r) {
            int q = q0 + quad * 4 + r;
            int t = t0 + lo;
            float w0 = (q >= t)      ? exp2f((float)(q - t) * lg2)      : 0.0f;
            float w1 = (q >= t + 16) ? exp2f((float)(q - t - 16) * lg2) : 0.0f;
            Pw[(quad * 4 + r) * 40 + lo]      = f2bfs(s0[r] * w0);
            Pw[(quad * 4 + r) * 40 + 16 + lo] = f2bfs(s1[r] * w1);
        }
        __syncthreads();   // LDS writes (V stage + P) -> visible & ordered before reads
        // P A-frag: P[lo][quad*8+j]
        short8 pf = *(const short8*)(Pw + lo * 40 + quad * 8);
        // V B-frags: B[k=t][n=d] -> column reads from LDS
        short8 vf0, vf1;
        #pragma unroll
        for (int j = 0; j < 8; ++j) {
            vf0[j] = Vw[(quad * 8 + j) * VSTRIDE + lo];
            vf1[j] = Vw[(quad * 8 + j) * VSTRIDE + 16 + lo];
        }
        o0 = __builtin_amdgcn_mfma_f32_16x16x32_bf16(pf, vf0, o0, 0, 0, 0);
        o1 = __builtin_amdgcn_mfma_f32_16x16x32_bf16(pf, vf1, o1, 0, 0, 0);
        __syncthreads();   // reads done before next iteration overwrites tiles
    }

    // epilogue: groupnorm over the 32 head dims of each row + silu(G) gate -> T (Q slot)
    float gw0 = gnw[h * HDIM + lo], gw1 = gnw[h * HDIM + 16 + lo];
    float gb0 = gnb[h * HDIM + lo], gb1 = gnb[h * HDIM + 16 + lo];
    bf16* QK = QKVG;
    #pragma unroll
    for (int r = 0; r < 4; ++r) {
        float y0 = o0[r], y1 = o1[r];
        float s = y0 + y1, ss = y0 * y0 + y1 * y1;
        #pragma unroll
        for (int off = 1; off < 16; off <<= 1) {
            s  += __shfl_xor(s, off);
            ss += __shfl_xor(ss, off);
        }
        float mu = s * (1.0f / HDIM);
        float var = ss * (1.0f / HDIM) - mu * mu;
        float rstd = rsqrtf(var + 1e-5f);
        int q = q0 + quad * 4 + r;
        size_t rowb = base + (size_t)q * 1024;
        float g0 = bf2f(QK[rowb + 768 + h * HDIM + lo]);
        float g1 = bf2f(QK[rowb + 768 + h * HDIM + 16 + lo]);
        float t0v = g0 / (1.0f + expf(-g0)) * ((y0 - mu) * rstd * gw0 + gb0);
        float t1v = g1 / (1.0f + expf(-g1)) * ((y1 - mu) * rstd * gw1 + gb1);
        QK[rowb + h * HDIM + lo]      = f2bf(t0v);
        QK[rowb + h * HDIM + 16 + lo] = f2bf(t1v);
    }
}

// ---------- generic tiled GEMM: C = act(Aeff @ W + bias) + addsrc ----------
template<bool ABF16, bool ALN, bool GELU, bool CBF16, bool BIAS, bool ADD>
__global__ __launch_bounds__(256) void gemm_t(const void* __restrict__ Av, int lda,
                                              const float* __restrict__ stats,
                                              const float* __restrict__ lnw,
                                              const float* __restrict__ lnb,
                                              const float* __restrict__ W,
                                              const float* __restrict__ bias,
                                              const float* __restrict__ addsrc, int ldadd,
                                              void* __restrict__ Cv, int ldc,
                                              int N, int K) {
    __shared__ float As[32][33];
    __shared__ float Bs[32][33];
    int tx = threadIdx.x, ty = threadIdx.y;
    int tid = ty * 16 + tx;
    int col0 = blockIdx.x * 32;
    int row0 = blockIdx.y * 32;
    float acc00 = 0.f, acc01 = 0.f, acc10 = 0.f, acc11 = 0.f;

    for (int k0 = 0; k0 < K; k0 += 32) {
        #pragma unroll
        for (int i = tid; i < 32 * 32; i += 256) {
            int r = i >> 5, c = i & 31;
            int row = row0 + r;
            int k = k0 + c;
            float a;
            if (ABF16) a = bf2f(((const bf16*)Av)[(size_t)row * lda + k]);
            else       a = ((const float*)Av)[(size_t)row * lda + k];
            if (ALN)   a = (a - stats[2 * row]) * stats[2 * row + 1] * lnw[k] + lnb[k];
            As[r][c] = a;
            Bs[r][c] = W[(size_t)(k0 + r) * N + col0 + c];
        }
        __syncthreads();
        #pragma unroll
        for (int k = 0; k < 32; ++k) {
            float a0 = As[2 * ty][k], a1 = As[2 * ty + 1][k];
            float b0 = Bs[k][2 * tx], b1 = Bs[k][2 * tx + 1];
            acc00 += a0 * b0; acc01 += a0 * b1;
            acc10 += a1 * b0; acc11 += a1 * b1;
        }
        __syncthreads();
    }

    float vals[2][2] = {{acc00, acc01}, {acc10, acc11}};
    #pragma unroll
    for (int ii = 0; ii < 2; ++ii) {
        #pragma unroll
        for (int jj = 0; jj < 2; ++jj) {
            int r = row0 + 2 * ty + ii;
            int c = col0 + 2 * tx + jj;
            float v = vals[ii][jj];
            if (BIAS) v += bias[c];
            if (GELU) v = 0.5f * v * (1.0f + erff(v * 0.70710678118f));
            if (ADD)  v += addsrc[(size_t)r * ldadd + c];
            if (CBF16) ((bf16*)Cv)[(size_t)r * ldc + c] = f2bf(v);
            else       ((float*)Cv)[(size_t)r * ldc + c] = v;
        }
    }
}

// ---------- final copy (f32 out) ----------
__global__ __launch_bounds__(256) void copy_kernel(const float* __restrict__ X,
                                                   float* __restrict__ out) {
    int idx = blockIdx.x * 256 + threadIdx.x;
    out[idx] = X[idx];
}

extern "C" void kernel_launch(void* const* d_in, const int* in_sizes, int n_in,
                              void* d_out, int out_size, void* d_ws, size_t ws_size,
                              hipStream_t stream) {
    const int*   v    = (const int*)d_in[0];
    const float* emb  = (const float*)d_in[1];
    const float* WQ   = (const float*)d_in[2];
    const float* WK   = (const float*)d_in[3];
    const float* WV   = (const float*)d_in[4];
    const float* WG   = (const float*)d_in[5];
    const float* WO   = (const float*)d_in[6];
    const float* gn_w = (const float*)d_in[7];
    const float* gn_b = (const float*)d_in[8];
    const float* ln1w = (const float*)d_in[9];
    const float* ln1b = (const float*)d_in[10];
    const float* ln2w = (const float*)d_in[11];
    const float* ln2b = (const float*)d_in[12];
    const float* w1   = (const float*)d_in[13];
    const float* b1   = (const float*)d_in[14];
    const float* w2   = (const float*)d_in[15];
    const float* b2   = (const float*)d_in[16];
    float* out = (float*)d_out;

    float* base  = (float*)d_ws;
    int*   flag  = (int*)base;
    float* X     = base + 16;
    float* stats = X + NELEM;
    bf16*  QKVG  = (bf16*)(stats + 2 * NROWS);
    bf16*  Hf    = QKVG + (size_t)NROWS * 1024;

    dim3 blk(16, 16);

    init_flag<<<1, 1, 0, stream>>>(flag);
    detect_v<<<32, 256, 0, stream>>>(v, flag);
    embed_kernel<<<NELEM / 256, 256, 0, stream>>>(v, emb, flag, X);

    for (int i = 0; i < 3; ++i) {
        const float* WQi = WQ + (size_t)i * HH * DD * HDIM;
        const float* WKi = WK + (size_t)i * HH * DD * HDIM;
        const float* WVi = WV + (size_t)i * HH * DD * HDIM;
        const float* WGi = WG + (size_t)i * DD * DD;
        const float* WOi = WO + (size_t)i * DD * DD;
        const float* w1i = w1 + (size_t)i * DD * FFNN;
        const float* w2i = w2 + (size_t)i * FFNN * DD;

        ln_stats_kernel<<<NROWS, 256, 0, stream>>>(X, stats);
        qkvg_kernel<<<dim3(32, NROWS / 32), blk, 0, stream>>>(X, stats, ln1w + i * DD, ln1b + i * DD,
                                                              WQi, WKi, WVi, WGi, QKVG);
        retention_mfma_kernel<<<2048, 256, 0, stream>>>(QKVG, gn_w + i * DD, gn_b + i * DD);
        // Y = T @ WO + X  (in-place over X)
        gemm_t<true, false, false, false, false, true>
            <<<dim3(8, NROWS / 32), blk, 0, stream>>>(QKVG, 1024, nullptr, nullptr, nullptr,
                                                      WOi, nullptr, X, DD, X, DD, DD, DD);
        ln_stats_kernel<<<NROWS, 256, 0, stream>>>(X, stats);
        gemm_t<false, true, true, true, true, false>
            <<<dim3(4, NROWS / 32), blk, 0, stream>>>(X, DD, stats, ln2w + i * DD, ln2b + i * DD,
                                                      w1i, b1 + i * FFNN, nullptr, 0, Hf, FFNN, FFNN, DD);
        gemm_t<true, false, false, false, true, true>
            <<<dim3(8, NROWS / 32), blk, 0, stream>>>(Hf, FFNN, nullptr, nullptr, nullptr,
                                                      w2i, b2 + i * DD, X, DD, X, DD, DD, FFNN);
    }

    copy_kernel<<<NELEM / 256, 256, 0, stream>>>(X, out);
}

// Round 5
// 944.230 us; speedup vs baseline: 3.2758x; 1.7757x over previous
//
#include <hip/hip_runtime.h>
#include <hip/hip_bf16.h>
#include <math.h>

#define BB 32
#define SS 512
#define DD 256
#define HH 8
#define HDIM 32
#define FFNN 128
#define NROWS (BB*SS)        // 16384
#define NELEM (NROWS*DD)     // 4194304

using bf16 = __hip_bfloat16;
typedef __attribute__((ext_vector_type(8))) short short8;
typedef __attribute__((ext_vector_type(4))) float floatx4;

static __device__ __forceinline__ float bf2f(bf16 x) { return __bfloat162float(x); }
static __device__ __forceinline__ bf16  f2bf(float x) { return __float2bfloat16(x); }
static __device__ __forceinline__ short f2bfs(float x) {
    bf16 b = __float2bfloat16(x);
    return __builtin_bit_cast(short, b);
}

// ---------- v dtype probe ----------
__global__ void init_flag(int* flag) { *flag = 0; }
__global__ __launch_bounds__(256) void detect_v(const int* __restrict__ v, int* __restrict__ flag) {
    int i = blockIdx.x * 256 + threadIdx.x;
    if (v[2 * i + 1] != 0) atomicOr(flag, 1);
}

// ---------- embed: X = relu(emb[v]), emb row 0 forced to 0; X lives in d_out ----------
__global__ __launch_bounds__(256) void embed_kernel(const int* __restrict__ v,
                                                    const float* __restrict__ emb,
                                                    const int* __restrict__ flag,
                                                    float* __restrict__ X) {
    int idx = blockIdx.x * 256 + threadIdx.x;
    int d = idx & (DD - 1);
    int row = idx >> 8;
    int tok = (*flag) ? v[row] : v[2 * row];
    float val = 0.0f;
    if (tok != 0) {
        val = emb[tok * DD + d];
        val = val > 0.0f ? val : 0.0f;
    }
    X[idx] = val;
}

// ---------- per-row layernorm stats ----------
__global__ __launch_bounds__(256) void ln_stats_kernel(const float* __restrict__ X,
                                                       float* __restrict__ stats) {
    int row = blockIdx.x;
    float x = X[(size_t)row * DD + threadIdx.x];
    float s1 = x, s2 = x * x;
    #pragma unroll
    for (int off = 1; off < 64; off <<= 1) {
        s1 += __shfl_xor(s1, off);
        s2 += __shfl_xor(s2, off);
    }
    __shared__ float p1[4], p2[4];
    int wid = threadIdx.x >> 6;
    if ((threadIdx.x & 63) == 0) { p1[wid] = s1; p2[wid] = s2; }
    __syncthreads();
    if (threadIdx.x == 0) {
        float t1 = p1[0] + p1[1] + p1[2] + p1[3];
        float t2 = p2[0] + p2[1] + p2[2] + p2[3];
        float mu = t1 * (1.0f / DD);
        float var = t2 * (1.0f / DD) - mu * mu;
        stats[2 * row] = mu;
        stats[2 * row + 1] = rsqrtf(var + 1e-5f);
    }
}

// ---------- weight packing: f32 -> bf16, [n][k] layout (B-frag contiguous) ----------
__global__ __launch_bounds__(256) void pack_qkvg(const float* __restrict__ WQ, const float* __restrict__ WK,
                                                 const float* __restrict__ WV, const float* __restrict__ WG,
                                                 bf16* __restrict__ dst) {
    int idx = blockIdx.x * 256 + threadIdx.x;       // 3*1024*256
    int k = idx & 255, n = (idx >> 8) & 1023, l = idx >> 18;
    int seg = n >> 8, n8 = n & 255;
    float val;
    if (seg < 3) {
        const float* W = (seg == 0) ? WQ : (seg == 1) ? WK : WV;
        int h = n8 >> 5, e = n8 & 31;
        val = W[(((size_t)l * 8 + h) * 256 + k) * 32 + e];
    } else {
        val = WG[(size_t)l * 65536 + k * 256 + n8];
    }
    dst[((size_t)l * 1024 + n) * 256 + k] = f2bf(val);
}
__global__ __launch_bounds__(256) void pack_wo(const float* __restrict__ WO, bf16* __restrict__ dst) {
    int idx = blockIdx.x * 256 + threadIdx.x;       // 3*256*256
    int k = idx & 255, n = (idx >> 8) & 255, l = idx >> 16;
    dst[((size_t)l * 256 + n) * 256 + k] = f2bf(WO[(size_t)l * 65536 + k * 256 + n]);
}
__global__ __launch_bounds__(256) void pack_w1(const float* __restrict__ w1, bf16* __restrict__ dst) {
    int idx = blockIdx.x * 256 + threadIdx.x;       // 3*128*256
    int k = idx & 255, n = (idx >> 8) & 127, l = idx >> 15;
    dst[((size_t)l * 128 + n) * 256 + k] = f2bf(w1[(size_t)l * 32768 + k * 128 + n]);
}
__global__ __launch_bounds__(256) void pack_w2(const float* __restrict__ w2, bf16* __restrict__ dst) {
    int idx = blockIdx.x * 256 + threadIdx.x;       // 3*256*128
    int k = idx & 127, n = (idx >> 7) & 255, l = idx >> 15;
    dst[((size_t)l * 256 + n) * 128 + k] = f2bf(w2[(size_t)l * 32768 + k * 256 + n]);
}

// ---------- MFMA GEMM: 128x128 tile, BK=64, 4 waves x (4x4) 16x16x32 tiles ----------
// MODEA: 0 = f32 source + LN (stats/lnw/lnb) -> bf16 ; 1 = bf16 source (lda in shorts)
// EPI:   0 = xPos rotation (cols<512) + bf16 store (qkvg, ldc=1024)
//        1 = optional bias + f32 residual add + f32 store
//        2 = bias + exact gelu + bf16 store
#define LSTR 72   // LDS row stride (shorts): 144B, 16B-aligned, b128-friendly
template<int MODEA, int EPI>
__global__ __launch_bounds__(256) void mfma_gemm(const void* __restrict__ Asrc, int lda,
                                                 const float* __restrict__ stats,
                                                 const float* __restrict__ lnw,
                                                 const float* __restrict__ lnb,
                                                 const bf16* __restrict__ Bp,   // [N][K] packed
                                                 const float* __restrict__ bias,
                                                 const float* __restrict__ addsrc, int ldadd,
                                                 void* __restrict__ Cv, int ldc,
                                                 int K) {
    __shared__ __align__(16) short Als[128 * LSTR];
    __shared__ __align__(16) short Bls[128 * LSTR];
    const int tid = threadIdx.x;
    const int wave = tid >> 6, lane = tid & 63, lo = lane & 15, quad = lane >> 4;
    const int wm = wave >> 1, wn = wave & 1;
    const int row0 = blockIdx.y * 128, col0 = blockIdx.x * 128;

    floatx4 acc[4][4];
    #pragma unroll
    for (int i = 0; i < 4; ++i)
        #pragma unroll
        for (int j = 0; j < 4; ++j) acc[i][j] = floatx4{0.f, 0.f, 0.f, 0.f};

    for (int k0 = 0; k0 < K; k0 += 64) {
        // ---- stage A tile [128 x 64] ----
        if (MODEA == 0) {
            const float* Xs = (const float*)Asrc;
            int r = tid >> 4, c4 = tid & 15;
            #pragma unroll
            for (int it = 0; it < 8; ++it, r += 16) {
                int row = row0 + r;
                const float4 x4 = *(const float4*)(Xs + (size_t)row * lda + k0 + c4 * 4);
                float mu = stats[2 * row], rs = stats[2 * row + 1];
                int k = k0 + c4 * 4;
                short4 o;
                o.x = f2bfs((x4.x - mu) * rs * lnw[k]     + lnb[k]);
                o.y = f2bfs((x4.y - mu) * rs * lnw[k + 1] + lnb[k + 1]);
                o.z = f2bfs((x4.z - mu) * rs * lnw[k + 2] + lnb[k + 2]);
                o.w = f2bfs((x4.w - mu) * rs * lnw[k + 3] + lnb[k + 3]);
                *(short4*)(&Als[r * LSTR + c4 * 4]) = o;
            }
        } else {
            const short* As16 = (const short*)Asrc;
            int r = tid >> 3, c8 = tid & 7;
            #pragma unroll
            for (int it = 0; it < 4; ++it, r += 32) {
                short8 vv = *(const short8*)(As16 + (size_t)(row0 + r) * lda + k0 + c8 * 8);
                *(short8*)(&Als[r * LSTR + c8 * 8]) = vv;
            }
        }
        // ---- stage B tile [128n x 64k] from packed [n][k] ----
        {
            const short* Bs16 = (const short*)Bp;
            int n = tid >> 3, c8 = tid & 7;
            #pragma unroll
            for (int it = 0; it < 4; ++it, n += 32) {
                short8 vv = *(const short8*)(Bs16 + (size_t)(col0 + n) * K + k0 + c8 * 8);
                *(short8*)(&Bls[n * LSTR + c8 * 8]) = vv;
            }
        }
        __syncthreads();
        #pragma unroll
        for (int kk = 0; kk < 64; kk += 32) {
            short8 af[4], bfr[4];
            #pragma unroll
            for (int t = 0; t < 4; ++t)
                af[t] = *(const short8*)(&Als[(wm * 64 + t * 16 + lo) * LSTR + kk + quad * 8]);
            #pragma unroll
            for (int t = 0; t < 4; ++t)
                bfr[t] = *(const short8*)(&Bls[(wn * 64 + t * 16 + lo) * LSTR + kk + quad * 8]);
            #pragma unroll
            for (int ti = 0; ti < 4; ++ti)
                #pragma unroll
                for (int tj = 0; tj < 4; ++tj)
                    acc[ti][tj] = __builtin_amdgcn_mfma_f32_16x16x32_bf16(af[ti], bfr[tj], acc[ti][tj], 0, 0, 0);
        }
        __syncthreads();
    }

    // ---- epilogue: C/D layout col=lo, row=quad*4+r ----
    #pragma unroll
    for (int ti = 0; ti < 4; ++ti) {
        #pragma unroll
        for (int tj = 0; tj < 4; ++tj) {
            int colb = col0 + wn * 64 + tj * 16 + lo;
            #pragma unroll
            for (int r = 0; r < 4; ++r) {
                int row = row0 + wm * 64 + ti * 16 + quad * 4 + r;
                float v = acc[ti][tj][r];
                if (EPI == 0) {
                    int seg = colb >> 8;            // wave-uniform
                    if (seg < 2) {
                        int s = row & (SS - 1);
                        int jf = (colb & 31) >> 1;
                        float base = (2.0f * jf + 12.8f) / 44.8f;
                        float sm = powf(base, (float)s * (1.0f / 512.0f));
                        if (seg == 1) sm = 1.0f / sm;
                        float sn, cs;
                        sincosf((float)s * powf(10000.0f, -(float)jf / 16.0f), &sn, &cs);
                        float p = __shfl_xor(v, 1);
                        v = (lo & 1) ? (v * cs + p * sn) * sm : (v * cs - p * sn) * sm;
                    }
                    ((bf16*)Cv)[(size_t)row * ldc + colb] = f2bf(v);
                } else if (EPI == 1) {
                    if (bias) v += bias[colb];
                    v += addsrc[(size_t)row * ldadd + colb];
                    ((float*)Cv)[(size_t)row * ldc + colb] = v;
                } else {
                    v += bias[colb];
                    v = 0.5f * v * (1.0f + erff(v * 0.70710678118f));
                    ((bf16*)Cv)[(size_t)row * ldc + colb] = f2bf(v);
                }
            }
        }
    }
}

// ---------- MFMA retention + groupnorm(32) + silu gate (unchanged from round 4) ----------
#define VSTRIDE 42
__global__ __launch_bounds__(256) void retention_mfma_kernel(bf16* __restrict__ QKVG,
                                                             const float* __restrict__ gnw,
                                                             const float* __restrict__ gnb) {
    __shared__ __align__(16) short Vl[4][32 * VSTRIDE];
    __shared__ __align__(16) short Pl[4][16 * 40];
    int wslot = threadIdx.x >> 6;
    int lane = threadIdx.x & 63;
    int qi = blockIdx.x >> 6;
    int bh = ((blockIdx.x & 63) << 2) | wslot;
    int b = bh >> 3, h = bh & 7;
    int q0 = qi * 16;
    int lo = lane & 15, quad = lane >> 4;

    const float la0 = -3.46573590280f, la1 = -6.23832462504f;
    float gamma = 1.0f - expf(la0 + (float)h * (la1 - la0) / 7.0f);
    float lg2 = log2f(gamma);

    const size_t base = (size_t)b * SS * 1024;
    const short* QKVGs = (const short*)QKVG;

    short8 qfrag = *(const short8*)(QKVGs + base + (size_t)(q0 + lo) * 1024 + h * HDIM + quad * 8);

    floatx4 o0 = {0.f, 0.f, 0.f, 0.f}, o1 = {0.f, 0.f, 0.f, 0.f};
    short* Vw = Vl[wslot];
    short* Pw = Pl[wslot];
    int nch = (qi >> 1) + 1;

    for (int ch = 0; ch < nch; ++ch) {
        int t0 = ch * 32;
        const short* Kb = QKVGs + base + 256 + h * HDIM + quad * 8;
        short8 kf0 = *(const short8*)(Kb + (size_t)(t0 + lo) * 1024);
        short8 kf1 = *(const short8*)(Kb + (size_t)(t0 + 16 + lo) * 1024);
        {
            int r = lane >> 2, d = (lane & 3) * 8;
            const uint* Vg1 = (const uint*)(QKVGs + base + (size_t)(t0 + r) * 1024 + 512 + h * HDIM + d);
            const uint* Vg2 = (const uint*)(QKVGs + base + (size_t)(t0 + 16 + r) * 1024 + 512 + h * HDIM + d);
            uint* L1 = (uint*)(Vw + r * VSTRIDE + d);
            uint* L2 = (uint*)(Vw + (16 + r) * VSTRIDE + d);
            #pragma unroll
            for (int w = 0; w < 4; ++w) { L1[w] = Vg1[w]; L2[w] = Vg2[w]; }
        }
        floatx4 z = {0.f, 0.f, 0.f, 0.f};
        floatx4 s0 = __builtin_amdgcn_mfma_f32_16x16x32_bf16(qfrag, kf0, z, 0, 0, 0);
        floatx4 s1 = __builtin_amdgcn_mfma_f32_16x16x32_bf16(qfrag, kf1, z, 0, 0, 0);
        #pragma unroll
        for (int r = 0; r < 4; ++r) {
            int q = q0 + quad * 4 + r;
            int t = t0 + lo;
            float w0 = (q >= t)      ? exp2f((float)(q - t) * lg2)      : 0.0f;
            float w1 = (q >= t + 16) ? exp2f((float)(q - t - 16) * lg2) : 0.0f;
            Pw[(quad * 4 + r) * 40 + lo]      = f2bfs(s0[r] * w0);
            Pw[(quad * 4 + r) * 40 + 16 + lo] = f2bfs(s1[r] * w1);
        }
        __syncthreads();
        short8 pf = *(const short8*)(Pw + lo * 40 + quad * 8);
        short8 vf0, vf1;
        #pragma unroll
        for (int j = 0; j < 8; ++j) {
            vf0[j] = Vw[(quad * 8 + j) * VSTRIDE + lo];
            vf1[j] = Vw[(quad * 8 + j) * VSTRIDE + 16 + lo];
        }
        o0 = __builtin_amdgcn_mfma_f32_16x16x32_bf16(pf, vf0, o0, 0, 0, 0);
        o1 = __builtin_amdgcn_mfma_f32_16x16x32_bf16(pf, vf1, o1, 0, 0, 0);
        __syncthreads();
    }

    float gw0 = gnw[h * HDIM + lo], gw1 = gnw[h * HDIM + 16 + lo];
    float gb0 = gnb[h * HDIM + lo], gb1 = gnb[h * HDIM + 16 + lo];
    bf16* QK = QKVG;
    #pragma unroll
    for (int r = 0; r < 4; ++r) {
        float y0 = o0[r], y1 = o1[r];
        float s = y0 + y1, ss = y0 * y0 + y1 * y1;
        #pragma unroll
        for (int off = 1; off < 16; off <<= 1) {
            s  += __shfl_xor(s, off);
            ss += __shfl_xor(ss, off);
        }
        float mu = s * (1.0f / HDIM);
        float var = ss * (1.0f / HDIM) - mu * mu;
        float rstd = rsqrtf(var + 1e-5f);
        int q = q0 + quad * 4 + r;
        size_t rowb = base + (size_t)q * 1024;
        float g0 = bf2f(QK[rowb + 768 + h * HDIM + lo]);
        float g1 = bf2f(QK[rowb + 768 + h * HDIM + 16 + lo]);
        float t0v = g0 / (1.0f + expf(-g0)) * ((y0 - mu) * rstd * gw0 + gb0);
        float t1v = g1 / (1.0f + expf(-g1)) * ((y1 - mu) * rstd * gw1 + gb1);
        QK[rowb + h * HDIM + lo]      = f2bf(t0v);
        QK[rowb + h * HDIM + 16 + lo] = f2bf(t1v);
    }
}

extern "C" void kernel_launch(void* const* d_in, const int* in_sizes, int n_in,
                              void* d_out, int out_size, void* d_ws, size_t ws_size,
                              hipStream_t stream) {
    const int*   v    = (const int*)d_in[0];
    const float* emb  = (const float*)d_in[1];
    const float* WQ   = (const float*)d_in[2];
    const float* WK   = (const float*)d_in[3];
    const float* WV   = (const float*)d_in[4];
    const float* WG   = (const float*)d_in[5];
    const float* WO   = (const float*)d_in[6];
    const float* gn_w = (const float*)d_in[7];
    const float* gn_b = (const float*)d_in[8];
    const float* ln1w = (const float*)d_in[9];
    const float* ln1b = (const float*)d_in[10];
    const float* ln2w = (const float*)d_in[11];
    const float* ln2b = (const float*)d_in[12];
    const float* w1   = (const float*)d_in[13];
    const float* b1   = (const float*)d_in[14];
    const float* w2   = (const float*)d_in[15];
    const float* b2   = (const float*)d_in[16];

    float* X = (float*)d_out;                    // residual stream lives in d_out (f32)

    float* base  = (float*)d_ws;
    int*   flag  = (int*)base;
    float* stats = base + 16;                    // 2*NROWS floats
    bf16*  QKVG  = (bf16*)(stats + 2 * NROWS);   // NROWS*1024
    bf16*  Hf    = QKVG + (size_t)NROWS * 1024;  // NROWS*128
    bf16*  WqkvgP = Hf + (size_t)NROWS * 128;    // 3*1024*256
    bf16*  WoP   = WqkvgP + 3 * 1024 * 256;      // 3*256*256
    bf16*  W1P   = WoP + 3 * 256 * 256;          // 3*128*256
    bf16*  W2P   = W1P + 3 * 128 * 256;          // 3*256*128

    init_flag<<<1, 1, 0, stream>>>(flag);
    detect_v<<<32, 256, 0, stream>>>(v, flag);
    embed_kernel<<<NELEM / 256, 256, 0, stream>>>(v, emb, flag, X);
    pack_qkvg<<<3072, 256, 0, stream>>>(WQ, WK, WV, WG, WqkvgP);
    pack_wo<<<768, 256, 0, stream>>>(WO, WoP);
    pack_w1<<<384, 256, 0, stream>>>(w1, W1P);
    pack_w2<<<384, 256, 0, stream>>>(w2, W2P);

    for (int i = 0; i < 3; ++i) {
        ln_stats_kernel<<<NROWS, 256, 0, stream>>>(X, stats);
        // QKVG = xpos(LN1(X) @ [WQ|WK|WV|WG])  (bf16)
        mfma_gemm<0, 0><<<dim3(8, 128), 256, 0, stream>>>(X, DD, stats, ln1w + i * DD, ln1b + i * DD,
                                                          WqkvgP + (size_t)i * 1024 * 256,
                                                          nullptr, nullptr, 0, QKVG, 1024, 256);
        retention_mfma_kernel<<<2048, 256, 0, stream>>>(QKVG, gn_w + i * DD, gn_b + i * DD);
        // X += T @ WO
        mfma_gemm<1, 1><<<dim3(2, 128), 256, 0, stream>>>(QKVG, 1024, nullptr, nullptr, nullptr,
                                                          WoP + (size_t)i * 256 * 256,
                                                          nullptr, X, DD, X, DD, 256);
        ln_stats_kernel<<<NROWS, 256, 0, stream>>>(X, stats);
        // Hf = gelu(LN2(X) @ w1 + b1)  (bf16)
        mfma_gemm<0, 2><<<dim3(1, 128), 256, 0, stream>>>(X, DD, stats, ln2w + i * DD, ln2b + i * DD,
                                                          W1P + (size_t)i * 128 * 256,
                                                          b1 + i * FFNN, nullptr, 0, Hf, FFNN, 256);
        // X += Hf @ w2 + b2
        mfma_gemm<1, 1><<<dim3(2, 128), 256, 0, stream>>>(Hf, FFNN, nullptr, nullptr, nullptr,
                                                          W2P + (size_t)i * 256 * 128,
                                                          b2 + i * DD, X, DD, X, DD, 128);
    }
}

// Round 6
// 733.354 us; speedup vs baseline: 4.2178x; 1.2876x over previous
//
#include <hip/hip_runtime.h>
#include <hip/hip_bf16.h>
#include <math.h>

#define BB 32
#define SS 512
#define DD 256
#define HH 8
#define HDIM 32
#define FFNN 128
#define NROWS (BB*SS)        // 16384
#define NELEM (NROWS*DD)     // 4194304

using bf16 = __hip_bfloat16;
typedef __attribute__((ext_vector_type(8))) short short8;
typedef __attribute__((ext_vector_type(4))) float floatx4;

static __device__ __forceinline__ float bf2f(bf16 x) { return __bfloat162float(x); }
static __device__ __forceinline__ bf16  f2bf(float x) { return __float2bfloat16(x); }
static __device__ __forceinline__ short f2bfs(float x) {
    bf16 b = __float2bfloat16(x);
    return __builtin_bit_cast(short, b);
}

// ---------- v dtype probe ----------
__global__ void init_flag(int* flag) { *flag = 0; }
__global__ __launch_bounds__(256) void detect_v(const int* __restrict__ v, int* __restrict__ flag) {
    int i = blockIdx.x * 256 + threadIdx.x;
    if (v[2 * i + 1] != 0) atomicOr(flag, 1);
}

// ---------- embed: X = relu(emb[v]), emb row 0 forced to 0; X lives in d_out ----------
__global__ __launch_bounds__(256) void embed_kernel(const int* __restrict__ v,
                                                    const float* __restrict__ emb,
                                                    const int* __restrict__ flag,
                                                    float* __restrict__ X) {
    int idx = blockIdx.x * 256 + threadIdx.x;
    int d = idx & (DD - 1);
    int row = idx >> 8;
    int tok = (*flag) ? v[row] : v[2 * row];
    float val = 0.0f;
    if (tok != 0) {
        val = emb[tok * DD + d];
        val = val > 0.0f ? val : 0.0f;
    }
    X[idx] = val;
}

// ---------- xPos tables: xpt[s*16+jf] = {cos*sm, sin*sm, cos/sm, sin/sm} ----------
__global__ __launch_bounds__(256) void xpos_table_kernel(float4* __restrict__ xpt) {
    int idx = blockIdx.x * 256 + threadIdx.x;    // 8192 = 512*16
    int jf = idx & 15, s = idx >> 4;
    float base = (2.0f * jf + 12.8f) / 44.8f;
    float sm = powf(base, (float)s * (1.0f / 512.0f));
    float ang = (float)s * powf(10000.0f, -(float)jf / 16.0f);
    float sn, cs;
    sincosf(ang, &sn, &cs);
    xpt[idx] = float4{cs * sm, sn * sm, cs / sm, sn / sm};
}

// ---------- per-row layernorm stats ----------
__global__ __launch_bounds__(256) void ln_stats_kernel(const float* __restrict__ X,
                                                       float* __restrict__ stats) {
    int row = blockIdx.x;
    float x = X[(size_t)row * DD + threadIdx.x];
    float s1 = x, s2 = x * x;
    #pragma unroll
    for (int off = 1; off < 64; off <<= 1) {
        s1 += __shfl_xor(s1, off);
        s2 += __shfl_xor(s2, off);
    }
    __shared__ float p1[4], p2[4];
    int wid = threadIdx.x >> 6;
    if ((threadIdx.x & 63) == 0) { p1[wid] = s1; p2[wid] = s2; }
    __syncthreads();
    if (threadIdx.x == 0) {
        float t1 = p1[0] + p1[1] + p1[2] + p1[3];
        float t2 = p2[0] + p2[1] + p2[2] + p2[3];
        float mu = t1 * (1.0f / DD);
        float var = t2 * (1.0f / DD) - mu * mu;
        stats[2 * row] = mu;
        stats[2 * row + 1] = rsqrtf(var + 1e-5f);
    }
}

// ---------- weight packing: f32 -> bf16, [n][k] layout (B-frag contiguous) ----------
__global__ __launch_bounds__(256) void pack_qkvg(const float* __restrict__ WQ, const float* __restrict__ WK,
                                                 const float* __restrict__ WV, const float* __restrict__ WG,
                                                 bf16* __restrict__ dst) {
    int idx = blockIdx.x * 256 + threadIdx.x;       // 3*1024*256
    int k = idx & 255, n = (idx >> 8) & 1023, l = idx >> 18;
    int seg = n >> 8, n8 = n & 255;
    float val;
    if (seg < 3) {
        const float* W = (seg == 0) ? WQ : (seg == 1) ? WK : WV;
        int h = n8 >> 5, e = n8 & 31;
        val = W[(((size_t)l * 8 + h) * 256 + k) * 32 + e];
    } else {
        val = WG[(size_t)l * 65536 + k * 256 + n8];
    }
    dst[((size_t)l * 1024 + n) * 256 + k] = f2bf(val);
}
__global__ __launch_bounds__(256) void pack_wo(const float* __restrict__ WO, bf16* __restrict__ dst) {
    int idx = blockIdx.x * 256 + threadIdx.x;       // 3*256*256
    int k = idx & 255, n = (idx >> 8) & 255, l = idx >> 16;
    dst[((size_t)l * 256 + n) * 256 + k] = f2bf(WO[(size_t)l * 65536 + k * 256 + n]);
}
__global__ __launch_bounds__(256) void pack_w1(const float* __restrict__ w1, bf16* __restrict__ dst) {
    int idx = blockIdx.x * 256 + threadIdx.x;       // 3*128*256
    int k = idx & 255, n = (idx >> 8) & 127, l = idx >> 15;
    dst[((size_t)l * 128 + n) * 256 + k] = f2bf(w1[(size_t)l * 32768 + k * 128 + n]);
}
__global__ __launch_bounds__(256) void pack_w2(const float* __restrict__ w2, bf16* __restrict__ dst) {
    int idx = blockIdx.x * 256 + threadIdx.x;       // 3*256*128
    int k = idx & 127, n = (idx >> 7) & 255, l = idx >> 15;
    dst[((size_t)l * 256 + n) * 128 + k] = f2bf(w2[(size_t)l * 32768 + k * 256 + n]);
}

// ---------- MFMA GEMM: 128x128 tile, BK=64, 4 waves x (4x4) 16x16x32 tiles ----------
// MODEA: 0 = f32 source + LN (stats/lnw/lnb) -> bf16 ; 1 = bf16 source (lda in shorts)
// EPI:   0 = xPos rotation via table (cols<512) + bf16 store (qkvg, ldc=1024)
//        1 = optional bias + f32 residual add + f32 store
//        2 = bias + exact gelu + bf16 store
#define LSTR 72   // LDS row stride (shorts): 144B, 16B-aligned, b128-friendly
template<int MODEA, int EPI>
__global__ __launch_bounds__(256) void mfma_gemm(const void* __restrict__ Asrc, int lda,
                                                 const float* __restrict__ stats,
                                                 const float* __restrict__ lnw,
                                                 const float* __restrict__ lnb,
                                                 const bf16* __restrict__ Bp,   // [N][K] packed
                                                 const float* __restrict__ bias,
                                                 const float* __restrict__ addsrc, int ldadd,
                                                 const float4* __restrict__ xpt,
                                                 void* __restrict__ Cv, int ldc,
                                                 int K) {
    __shared__ __align__(16) short Als[128 * LSTR];
    __shared__ __align__(16) short Bls[128 * LSTR];
    const int tid = threadIdx.x;
    const int wave = tid >> 6, lane = tid & 63, lo = lane & 15, quad = lane >> 4;
    const int wm = wave >> 1, wn = wave & 1;
    const int row0 = blockIdx.y * 128, col0 = blockIdx.x * 128;

    floatx4 acc[4][4];
    #pragma unroll
    for (int i = 0; i < 4; ++i)
        #pragma unroll
        for (int j = 0; j < 4; ++j) acc[i][j] = floatx4{0.f, 0.f, 0.f, 0.f};

    for (int k0 = 0; k0 < K; k0 += 64) {
        // ---- stage A tile [128 x 64] ----
        if (MODEA == 0) {
            const float* Xs = (const float*)Asrc;
            int r = tid >> 4, c4 = tid & 15;
            #pragma unroll
            for (int it = 0; it < 8; ++it, r += 16) {
                int row = row0 + r;
                const float4 x4 = *(const float4*)(Xs + (size_t)row * lda + k0 + c4 * 4);
                float mu = stats[2 * row], rs = stats[2 * row + 1];
                int k = k0 + c4 * 4;
                short4 o;
                o.x = f2bfs((x4.x - mu) * rs * lnw[k]     + lnb[k]);
                o.y = f2bfs((x4.y - mu) * rs * lnw[k + 1] + lnb[k + 1]);
                o.z = f2bfs((x4.z - mu) * rs * lnw[k + 2] + lnb[k + 2]);
                o.w = f2bfs((x4.w - mu) * rs * lnw[k + 3] + lnb[k + 3]);
                *(short4*)(&Als[r * LSTR + c4 * 4]) = o;
            }
        } else {
            const short* As16 = (const short*)Asrc;
            int r = tid >> 3, c8 = tid & 7;
            #pragma unroll
            for (int it = 0; it < 4; ++it, r += 32) {
                short8 vv = *(const short8*)(As16 + (size_t)(row0 + r) * lda + k0 + c8 * 8);
                *(short8*)(&Als[r * LSTR + c8 * 8]) = vv;
            }
        }
        // ---- stage B tile [128n x 64k] from packed [n][k] ----
        {
            const short* Bs16 = (const short*)Bp;
            int n = tid >> 3, c8 = tid & 7;
            #pragma unroll
            for (int it = 0; it < 4; ++it, n += 32) {
                short8 vv = *(const short8*)(Bs16 + (size_t)(col0 + n) * K + k0 + c8 * 8);
                *(short8*)(&Bls[n * LSTR + c8 * 8]) = vv;
            }
        }
        __syncthreads();
        #pragma unroll
        for (int kk = 0; kk < 64; kk += 32) {
            short8 af[4], bfr[4];
            #pragma unroll
            for (int t = 0; t < 4; ++t)
                af[t] = *(const short8*)(&Als[(wm * 64 + t * 16 + lo) * LSTR + kk + quad * 8]);
            #pragma unroll
            for (int t = 0; t < 4; ++t)
                bfr[t] = *(const short8*)(&Bls[(wn * 64 + t * 16 + lo) * LSTR + kk + quad * 8]);
            #pragma unroll
            for (int ti = 0; ti < 4; ++ti)
                #pragma unroll
                for (int tj = 0; tj < 4; ++tj)
                    acc[ti][tj] = __builtin_amdgcn_mfma_f32_16x16x32_bf16(af[ti], bfr[tj], acc[ti][tj], 0, 0, 0);
        }
        __syncthreads();
    }

    // ---- epilogue: C/D layout col=lo, row=quad*4+r ----
    #pragma unroll
    for (int ti = 0; ti < 4; ++ti) {
        #pragma unroll
        for (int tj = 0; tj < 4; ++tj) {
            int colb = col0 + wn * 64 + tj * 16 + lo;
            #pragma unroll
            for (int r = 0; r < 4; ++r) {
                int row = row0 + wm * 64 + ti * 16 + quad * 4 + r;
                float v = acc[ti][tj][r];
                if (EPI == 0) {
                    int seg = colb >> 8;            // wave-uniform
                    if (seg < 2) {
                        int s = row & (SS - 1);
                        int jf = (colb & 31) >> 1;
                        float4 t = xpt[s * 16 + jf];
                        float cs = (seg == 0) ? t.x : t.z;
                        float sn = (seg == 0) ? t.y : t.w;
                        float p = __shfl_xor(v, 1);
                        v = (lo & 1) ? (v * cs + p * sn) : (v * cs - p * sn);
                    }
                    ((bf16*)Cv)[(size_t)row * ldc + colb] = f2bf(v);
                } else if (EPI == 1) {
                    if (bias) v += bias[colb];
                    v += addsrc[(size_t)row * ldadd + colb];
                    ((float*)Cv)[(size_t)row * ldc + colb] = v;
                } else {
                    v += bias[colb];
                    v = 0.5f * v * (1.0f + erff(v * 0.70710678118f));
                    ((bf16*)Cv)[(size_t)row * ldc + colb] = f2bf(v);
                }
            }
        }
    }
}

// ---------- MFMA retention + groupnorm(32) + silu gate ----------
#define VSTRIDE 42
__global__ __launch_bounds__(256) void retention_mfma_kernel(bf16* __restrict__ QKVG,
                                                             const float* __restrict__ gnw,
                                                             const float* __restrict__ gnb) {
    __shared__ __align__(16) short Vl[4][32 * VSTRIDE];
    __shared__ __align__(16) short Pl[4][16 * 40];
    int wslot = threadIdx.x >> 6;
    int lane = threadIdx.x & 63;
    int qi = blockIdx.x >> 6;
    int bh = ((blockIdx.x & 63) << 2) | wslot;
    int b = bh >> 3, h = bh & 7;
    int q0 = qi * 16;
    int lo = lane & 15, quad = lane >> 4;

    const float la0 = -3.46573590280f, la1 = -6.23832462504f;
    float gamma = 1.0f - expf(la0 + (float)h * (la1 - la0) / 7.0f);
    float lg2 = log2f(gamma);

    const size_t base = (size_t)b * SS * 1024;
    const short* QKVGs = (const short*)QKVG;

    short8 qfrag = *(const short8*)(QKVGs + base + (size_t)(q0 + lo) * 1024 + h * HDIM + quad * 8);

    floatx4 o0 = {0.f, 0.f, 0.f, 0.f}, o1 = {0.f, 0.f, 0.f, 0.f};
    short* Vw = Vl[wslot];
    short* Pw = Pl[wslot];
    int nch = (qi >> 1) + 1;

    for (int ch = 0; ch < nch; ++ch) {
        int t0 = ch * 32;
        const short* Kb = QKVGs + base + 256 + h * HDIM + quad * 8;
        short8 kf0 = *(const short8*)(Kb + (size_t)(t0 + lo) * 1024);
        short8 kf1 = *(const short8*)(Kb + (size_t)(t0 + 16 + lo) * 1024);
        {
            int r = lane >> 2, d = (lane & 3) * 8;
            const uint* Vg1 = (const uint*)(QKVGs + base + (size_t)(t0 + r) * 1024 + 512 + h * HDIM + d);
            const uint* Vg2 = (const uint*)(QKVGs + base + (size_t)(t0 + 16 + r) * 1024 + 512 + h * HDIM + d);
            uint* L1 = (uint*)(Vw + r * VSTRIDE + d);
            uint* L2 = (uint*)(Vw + (16 + r) * VSTRIDE + d);
            #pragma unroll
            for (int w = 0; w < 4; ++w) { L1[w] = Vg1[w]; L2[w] = Vg2[w]; }
        }
        floatx4 z = {0.f, 0.f, 0.f, 0.f};
        floatx4 s0 = __builtin_amdgcn_mfma_f32_16x16x32_bf16(qfrag, kf0, z, 0, 0, 0);
        floatx4 s1 = __builtin_amdgcn_mfma_f32_16x16x32_bf16(qfrag, kf1, z, 0, 0, 0);
        #pragma unroll
        for (int r = 0; r < 4; ++r) {
            int q = q0 + quad * 4 + r;
            int t = t0 + lo;
            float w0 = (q >= t)      ? exp2f((float)(q - t) * lg2)      : 0.0f;
            float w1 = (q >= t + 16) ? exp2f((float)(q - t - 16) * lg2) : 0.0f;
            Pw[(quad * 4 + r) * 40 + lo]      = f2bfs(s0[r] * w0);
            Pw[(quad * 4 + r) * 40 + 16 + lo] = f2bfs(s1[r] * w1);
        }
        __syncthreads();
        short8 pf = *(const short8*)(Pw + lo * 40 + quad * 8);
        short8 vf0, vf1;
        #pragma unroll
        for (int j = 0; j < 8; ++j) {
            vf0[j] = Vw[(quad * 8 + j) * VSTRIDE + lo];
            vf1[j] = Vw[(quad * 8 + j) * VSTRIDE + 16 + lo];
        }
        o0 = __builtin_amdgcn_mfma_f32_16x16x32_bf16(pf, vf0, o0, 0, 0, 0);
        o1 = __builtin_amdgcn_mfma_f32_16x16x32_bf16(pf, vf1, o1, 0, 0, 0);
        __syncthreads();
    }

    float gw0 = gnw[h * HDIM + lo], gw1 = gnw[h * HDIM + 16 + lo];
    float gb0 = gnb[h * HDIM + lo], gb1 = gnb[h * HDIM + 16 + lo];
    bf16* QK = QKVG;
    #pragma unroll
    for (int r = 0; r < 4; ++r) {
        float y0 = o0[r], y1 = o1[r];
        float s = y0 + y1, ss = y0 * y0 + y1 * y1;
        #pragma unroll
        for (int off = 1; off < 16; off <<= 1) {
            s  += __shfl_xor(s, off);
            ss += __shfl_xor(ss, off);
        }
        float mu = s * (1.0f / HDIM);
        float var = ss * (1.0f / HDIM) - mu * mu;
        float rstd = rsqrtf(var + 1e-5f);
        int q = q0 + quad * 4 + r;
        size_t rowb = base + (size_t)q * 1024;
        float g0 = bf2f(QK[rowb + 768 + h * HDIM + lo]);
        float g1 = bf2f(QK[rowb + 768 + h * HDIM + 16 + lo]);
        float t0v = g0 / (1.0f + expf(-g0)) * ((y0 - mu) * rstd * gw0 + gb0);
        float t1v = g1 / (1.0f + expf(-g1)) * ((y1 - mu) * rstd * gw1 + gb1);
        QK[rowb + h * HDIM + lo]      = f2bf(t0v);
        QK[rowb + h * HDIM + 16 + lo] = f2bf(t1v);
    }
}

extern "C" void kernel_launch(void* const* d_in, const int* in_sizes, int n_in,
                              void* d_out, int out_size, void* d_ws, size_t ws_size,
                              hipStream_t stream) {
    const int*   v    = (const int*)d_in[0];
    const float* emb  = (const float*)d_in[1];
    const float* WQ   = (const float*)d_in[2];
    const float* WK   = (const float*)d_in[3];
    const float* WV   = (const float*)d_in[4];
    const float* WG   = (const float*)d_in[5];
    const float* WO   = (const float*)d_in[6];
    const float* gn_w = (const float*)d_in[7];
    const float* gn_b = (const float*)d_in[8];
    const float* ln1w = (const float*)d_in[9];
    const float* ln1b = (const float*)d_in[10];
    const float* ln2w = (const float*)d_in[11];
    const float* ln2b = (const float*)d_in[12];
    const float* w1   = (const float*)d_in[13];
    const float* b1   = (const float*)d_in[14];
    const float* w2   = (const float*)d_in[15];
    const float* b2   = (const float*)d_in[16];

    float* X = (float*)d_out;                    // residual stream lives in d_out (f32)

    float* base  = (float*)d_ws;
    int*   flag  = (int*)base;
    float* stats = base + 16;                    // 2*NROWS floats
    bf16*  QKVG  = (bf16*)(stats + 2 * NROWS);   // NROWS*1024
    bf16*  Hf    = QKVG + (size_t)NROWS * 1024;  // NROWS*128
    bf16*  WqkvgP = Hf + (size_t)NROWS * 128;    // 3*1024*256
    bf16*  WoP   = WqkvgP + 3 * 1024 * 256;      // 3*256*256
    bf16*  W1P   = WoP + 3 * 256 * 256;          // 3*128*256
    bf16*  W2P   = W1P + 3 * 128 * 256;          // 3*256*128
    float4* xpt  = (float4*)(W2P + 3 * 256 * 128); // 512*16 float4

    init_flag<<<1, 1, 0, stream>>>(flag);
    detect_v<<<32, 256, 0, stream>>>(v, flag);
    embed_kernel<<<NELEM / 256, 256, 0, stream>>>(v, emb, flag, X);
    xpos_table_kernel<<<32, 256, 0, stream>>>(xpt);
    pack_qkvg<<<3072, 256, 0, stream>>>(WQ, WK, WV, WG, WqkvgP);
    pack_wo<<<768, 256, 0, stream>>>(WO, WoP);
    pack_w1<<<384, 256, 0, stream>>>(w1, W1P);
    pack_w2<<<384, 256, 0, stream>>>(w2, W2P);

    for (int i = 0; i < 3; ++i) {
        ln_stats_kernel<<<NROWS, 256, 0, stream>>>(X, stats);
        // QKVG = xpos(LN1(X) @ [WQ|WK|WV|WG])  (bf16)
        mfma_gemm<0, 0><<<dim3(8, 128), 256, 0, stream>>>(X, DD, stats, ln1w + i * DD, ln1b + i * DD,
                                                          WqkvgP + (size_t)i * 1024 * 256,
                                                          nullptr, nullptr, 0, xpt, QKVG, 1024, 256);
        retention_mfma_kernel<<<2048, 256, 0, stream>>>(QKVG, gn_w + i * DD, gn_b + i * DD);
        // X += T @ WO
        mfma_gemm<1, 1><<<dim3(2, 128), 256, 0, stream>>>(QKVG, 1024, nullptr, nullptr, nullptr,
                                                          WoP + (size_t)i * 256 * 256,
                                                          nullptr, X, DD, nullptr, X, DD, 256);
        ln_stats_kernel<<<NROWS, 256, 0, stream>>>(X, stats);
        // Hf = gelu(LN2(X) @ w1 + b1)  (bf16)
        mfma_gemm<0, 2><<<dim3(1, 128), 256, 0, stream>>>(X, DD, stats, ln2w + i * DD, ln2b + i * DD,
                                                          W1P + (size_t)i * 128 * 256,
                                                          b1 + i * FFNN, nullptr, 0, nullptr, Hf, FFNN, 256);
        // X += Hf @ w2 + b2
        mfma_gemm<1, 1><<<dim3(2, 128), 256, 0, stream>>>(Hf, FFNN, nullptr, nullptr, nullptr,
                                                          W2P + (size_t)i * 256 * 128,
                                                          b2 + i * DD, X, DD, nullptr, X, DD, 128);
    }
}

// Round 7
// 564.589 us; speedup vs baseline: 5.4785x; 1.2989x over previous
//
#include <hip/hip_runtime.h>
#include <hip/hip_bf16.h>
#include <math.h>

#define BB 32
#define SS 512
#define DD 256
#define HH 8
#define HDIM 32
#define FFNN 128
#define NROWS (BB*SS)        // 16384
#define NELEM (NROWS*DD)     // 4194304

using bf16 = __hip_bfloat16;
typedef __attribute__((ext_vector_type(8))) short short8;
typedef __attribute__((ext_vector_type(4))) float floatx4;

static __device__ __forceinline__ float bf2f(bf16 x) { return __bfloat162float(x); }
static __device__ __forceinline__ bf16  f2bf(float x) { return __float2bfloat16(x); }
static __device__ __forceinline__ short f2bfs(float x) {
    bf16 b = __float2bfloat16(x);
    return __builtin_bit_cast(short, b);
}

// async global->LDS, 16B per lane; dest = wave-uniform base + lane*16
static __device__ __forceinline__ void gld_lds16(const void* g, void* l) {
    __builtin_amdgcn_global_load_lds(
        (const __attribute__((address_space(1))) void*)g,
        (__attribute__((address_space(3))) void*)l, 16, 0, 0);
}

// ---------- v dtype probe ----------
__global__ void init_flag(int* flag) { *flag = 0; }
__global__ __launch_bounds__(256) void detect_v(const int* __restrict__ v, int* __restrict__ flag) {
    int i = blockIdx.x * 256 + threadIdx.x;
    if (v[2 * i + 1] != 0) atomicOr(flag, 1);
}

// ---------- embed: X = relu(emb[v]), emb row 0 forced to 0; X lives in d_out ----------
__global__ __launch_bounds__(256) void embed_kernel(const int* __restrict__ v,
                                                    const float* __restrict__ emb,
                                                    const int* __restrict__ flag,
                                                    float* __restrict__ X) {
    int idx = blockIdx.x * 256 + threadIdx.x;
    int d = idx & (DD - 1);
    int row = idx >> 8;
    int tok = (*flag) ? v[row] : v[2 * row];
    float val = 0.0f;
    if (tok != 0) {
        val = emb[tok * DD + d];
        val = val > 0.0f ? val : 0.0f;
    }
    X[idx] = val;
}

// ---------- xPos tables: xpt[s*16+jf] = {cos*sm, sin*sm, cos/sm, sin/sm} ----------
__global__ __launch_bounds__(256) void xpos_table_kernel(float4* __restrict__ xpt) {
    int idx = blockIdx.x * 256 + threadIdx.x;    // 8192 = 512*16
    int jf = idx & 15, s = idx >> 4;
    float base = (2.0f * jf + 12.8f) / 44.8f;
    float sm = powf(base, (float)s * (1.0f / 512.0f));
    float ang = (float)s * powf(10000.0f, -(float)jf / 16.0f);
    float sn, cs;
    sincosf(ang, &sn, &cs);
    xpt[idx] = float4{cs * sm, sn * sm, cs / sm, sn / sm};
}

// ---------- fused layernorm: Xn = LN(X)*w+b  (bf16 out) ----------
__global__ __launch_bounds__(256) void ln_norm_kernel(const float* __restrict__ X,
                                                      const float* __restrict__ w,
                                                      const float* __restrict__ b,
                                                      short* __restrict__ Xn) {
    int row = blockIdx.x;
    int d = threadIdx.x;
    float x = X[(size_t)row * DD + d];
    float s1 = x, s2 = x * x;
    #pragma unroll
    for (int off = 1; off < 64; off <<= 1) {
        s1 += __shfl_xor(s1, off);
        s2 += __shfl_xor(s2, off);
    }
    __shared__ float p1[4], p2[4], st[2];
    int wid = threadIdx.x >> 6;
    if ((threadIdx.x & 63) == 0) { p1[wid] = s1; p2[wid] = s2; }
    __syncthreads();
    if (threadIdx.x == 0) {
        float t1 = p1[0] + p1[1] + p1[2] + p1[3];
        float t2 = p2[0] + p2[1] + p2[2] + p2[3];
        float mu = t1 * (1.0f / DD);
        float var = t2 * (1.0f / DD) - mu * mu;
        st[0] = mu; st[1] = rsqrtf(var + 1e-5f);
    }
    __syncthreads();
    Xn[(size_t)row * DD + d] = f2bfs((x - st[0]) * st[1] * w[d] + b[d]);
}

// ---------- weight packing: f32 -> bf16, [n][k] layout ----------
__global__ __launch_bounds__(256) void pack_qkvg(const float* __restrict__ WQ, const float* __restrict__ WK,
                                                 const float* __restrict__ WV, const float* __restrict__ WG,
                                                 bf16* __restrict__ dst) {
    int idx = blockIdx.x * 256 + threadIdx.x;       // 3*1024*256
    int k = idx & 255, n = (idx >> 8) & 1023, l = idx >> 18;
    int seg = n >> 8, n8 = n & 255;
    float val;
    if (seg < 3) {
        const float* W = (seg == 0) ? WQ : (seg == 1) ? WK : WV;
        int h = n8 >> 5, e = n8 & 31;
        val = W[(((size_t)l * 8 + h) * 256 + k) * 32 + e];
    } else {
        val = WG[(size_t)l * 65536 + k * 256 + n8];
    }
    dst[((size_t)l * 1024 + n) * 256 + k] = f2bf(val);
}
__global__ __launch_bounds__(256) void pack_wo(const float* __restrict__ WO, bf16* __restrict__ dst) {
    int idx = blockIdx.x * 256 + threadIdx.x;       // 3*256*256
    int k = idx & 255, n = (idx >> 8) & 255, l = idx >> 16;
    dst[((size_t)l * 256 + n) * 256 + k] = f2bf(WO[(size_t)l * 65536 + k * 256 + n]);
}
__global__ __launch_bounds__(256) void pack_w1(const float* __restrict__ w1, bf16* __restrict__ dst) {
    int idx = blockIdx.x * 256 + threadIdx.x;       // 3*128*256
    int k = idx & 255, n = (idx >> 8) & 127, l = idx >> 15;
    dst[((size_t)l * 128 + n) * 256 + k] = f2bf(w1[(size_t)l * 32768 + k * 128 + n]);
}
__global__ __launch_bounds__(256) void pack_w2(const float* __restrict__ w2, bf16* __restrict__ dst) {
    int idx = blockIdx.x * 256 + threadIdx.x;       // 3*256*128
    int k = idx & 127, n = (idx >> 7) & 255, l = idx >> 15;
    dst[((size_t)l * 256 + n) * 128 + k] = f2bf(w2[(size_t)l * 32768 + k * 256 + n]);
}

// ---------- MFMA GEMM, async-staged, fragment-ordered LDS ----------
// Block = 2x2 waves; per-wave TMxTN tiles of 16x16x32 -> BM=32*TM, BN=32*TN; BK=64.
// A: bf16 [M][lda]; B: bf16 packed [N][K].
// LDS groups of 1024B: A group (wm,t,kkgrp) holds rows (wm*TM+t)*16+(0..15),
// k-chunk kkgrp*32+(0..3)*8, in lane-linear order (stage lane i == read lane i).
// EPI: 0 = xPos via table (cols<512) + bf16 store; 1 = [bias]+f32 residual add/store;
//      2 = bias + exact gelu + bf16 store
template<int TM, int TN, int EPI>
__global__ __launch_bounds__(256) void mfma_gemm(const short* __restrict__ A, int lda,
                                                 const bf16* __restrict__ Bp,
                                                 const float* __restrict__ bias,
                                                 float* __restrict__ addsrc, int ldadd,
                                                 const float4* __restrict__ xpt,
                                                 void* __restrict__ Cv, int ldc,
                                                 int K) {
    __shared__ __align__(16) short Als[2 * TM * 2 * 512];
    __shared__ __align__(16) short Bls[2 * TN * 2 * 512];
    const int tid = threadIdx.x;
    const int wave = tid >> 6, lane = tid & 63, lo = lane & 15, quad = lane >> 4;
    const int wm = wave >> 1, wn = wave & 1;
    const int row0 = blockIdx.y * 32 * TM, col0 = blockIdx.x * 32 * TN;

    floatx4 acc[TM][TN];
    #pragma unroll
    for (int i = 0; i < TM; ++i)
        #pragma unroll
        for (int j = 0; j < TN; ++j) acc[i][j] = floatx4{0.f, 0.f, 0.f, 0.f};

    const short* Bs16 = (const short*)Bp;

    for (int k0 = 0; k0 < K; k0 += 64) {
        // wave (wm,wn) stages A groups (wm, t, kkgrp=wn) and B groups (wn, t, kkgrp=wm)
        #pragma unroll
        for (int t = 0; t < TM; ++t) {
            int grp = (wm * TM + t) * 2 + wn;
            const short* ga = A + (size_t)(row0 + (wm * TM + t) * 16 + lo) * lda
                            + k0 + (wn * 4 + quad) * 8;
            gld_lds16(ga, &Als[grp * 512]);
        }
        #pragma unroll
        for (int t = 0; t < TN; ++t) {
            int grp = (wn * TN + t) * 2 + wm;
            const short* gb = Bs16 + (size_t)(col0 + (wn * TN + t) * 16 + lo) * K
                            + k0 + (wm * 4 + quad) * 8;
            gld_lds16(gb, &Bls[grp * 512]);
        }
        __syncthreads();
        #pragma unroll
        for (int kkgrp = 0; kkgrp < 2; ++kkgrp) {
            short8 af[TM], bfr[TN];
            #pragma unroll
            for (int t = 0; t < TM; ++t)
                af[t] = *(const short8*)(&Als[((wm * TM + t) * 2 + kkgrp) * 512 + lane * 8]);
            #pragma unroll
            for (int t = 0; t < TN; ++t)
                bfr[t] = *(const short8*)(&Bls[((wn * TN + t) * 2 + kkgrp) * 512 + lane * 8]);
            #pragma unroll
            for (int ti = 0; ti < TM; ++ti)
                #pragma unroll
                for (int tj = 0; tj < TN; ++tj)
                    acc[ti][tj] = __builtin_amdgcn_mfma_f32_16x16x32_bf16(af[ti], bfr[tj], acc[ti][tj], 0, 0, 0);
        }
        __syncthreads();
    }

    // epilogue: C/D layout col=lo, row=quad*4+r
    #pragma unroll
    for (int ti = 0; ti < TM; ++ti) {
        #pragma unroll
        for (int tj = 0; tj < TN; ++tj) {
            int colb = col0 + (wn * TN + tj) * 16 + lo;
            #pragma unroll
            for (int r = 0; r < 4; ++r) {
                int row = row0 + (wm * TM + ti) * 16 + quad * 4 + r;
                float v = acc[ti][tj][r];
                if (EPI == 0) {
                    int seg = colb >> 8;            // wave-uniform
                    if (seg < 2) {
                        int s = row & (SS - 1);
                        int jf = (colb & 31) >> 1;
                        float4 t = xpt[s * 16 + jf];
                        float cs = (seg == 0) ? t.x : t.z;
                        float sn = (seg == 0) ? t.y : t.w;
                        float p = __shfl_xor(v, 1);
                        v = (lo & 1) ? (v * cs + p * sn) : (v * cs - p * sn);
                    }
                    ((bf16*)Cv)[(size_t)row * ldc + colb] = f2bf(v);
                } else if (EPI == 1) {
                    if (bias) v += bias[colb];
                    v += addsrc[(size_t)row * ldadd + colb];
                    ((float*)Cv)[(size_t)row * ldc + colb] = v;
                } else {
                    v += bias[colb];
                    v = 0.5f * v * (1.0f + erff(v * 0.70710678118f));
                    ((bf16*)Cv)[(size_t)row * ldc + colb] = f2bf(v);
                }
            }
        }
    }
}

// ---------- MFMA retention + groupnorm(32) + silu gate ----------
#define VSTRIDE 42
__global__ __launch_bounds__(256) void retention_mfma_kernel(bf16* __restrict__ QKVG,
                                                             const float* __restrict__ gnw,
                                                             const float* __restrict__ gnb) {
    __shared__ __align__(16) short Vl[4][32 * VSTRIDE];
    __shared__ __align__(16) short Pl[4][16 * 40];
    int wslot = threadIdx.x >> 6;
    int lane = threadIdx.x & 63;
    int qi = blockIdx.x >> 6;
    int bh = ((blockIdx.x & 63) << 2) | wslot;
    int b = bh >> 3, h = bh & 7;
    int q0 = qi * 16;
    int lo = lane & 15, quad = lane >> 4;

    const float la0 = -3.46573590280f, la1 = -6.23832462504f;
    float gamma = 1.0f - expf(la0 + (float)h * (la1 - la0) / 7.0f);
    float lg2 = log2f(gamma);

    const size_t base = (size_t)b * SS * 1024;
    const short* QKVGs = (const short*)QKVG;

    short8 qfrag = *(const short8*)(QKVGs + base + (size_t)(q0 + lo) * 1024 + h * HDIM + quad * 8);

    floatx4 o0 = {0.f, 0.f, 0.f, 0.f}, o1 = {0.f, 0.f, 0.f, 0.f};
    short* Vw = Vl[wslot];
    short* Pw = Pl[wslot];
    int nch = (qi >> 1) + 1;

    for (int ch = 0; ch < nch; ++ch) {
        int t0 = ch * 32;
        const short* Kb = QKVGs + base + 256 + h * HDIM + quad * 8;
        short8 kf0 = *(const short8*)(Kb + (size_t)(t0 + lo) * 1024);
        short8 kf1 = *(const short8*)(Kb + (size_t)(t0 + 16 + lo) * 1024);
        {
            int r = lane >> 2, d = (lane & 3) * 8;
            const uint* Vg1 = (const uint*)(QKVGs + base + (size_t)(t0 + r) * 1024 + 512 + h * HDIM + d);
            const uint* Vg2 = (const uint*)(QKVGs + base + (size_t)(t0 + 16 + r) * 1024 + 512 + h * HDIM + d);
            uint* L1 = (uint*)(Vw + r * VSTRIDE + d);
            uint* L2 = (uint*)(Vw + (16 + r) * VSTRIDE + d);
            #pragma unroll
            for (int w = 0; w < 4; ++w) { L1[w] = Vg1[w]; L2[w] = Vg2[w]; }
        }
        floatx4 z = {0.f, 0.f, 0.f, 0.f};
        floatx4 s0 = __builtin_amdgcn_mfma_f32_16x16x32_bf16(qfrag, kf0, z, 0, 0, 0);
        floatx4 s1 = __builtin_amdgcn_mfma_f32_16x16x32_bf16(qfrag, kf1, z, 0, 0, 0);
        #pragma unroll
        for (int r = 0; r < 4; ++r) {
            int q = q0 + quad * 4 + r;
            int t = t0 + lo;
            float w0 = (q >= t)      ? exp2f((float)(q - t) * lg2)      : 0.0f;
            float w1 = (q >= t + 16) ? exp2f((float)(q - t - 16) * lg2) : 0.0f;
            Pw[(quad * 4 + r) * 40 + lo]      = f2bfs(s0[r] * w0);
            Pw[(quad * 4 + r) * 40 + 16 + lo] = f2bfs(s1[r] * w1);
        }
        __syncthreads();
        short8 pf = *(const short8*)(Pw + lo * 40 + quad * 8);
        short8 vf0, vf1;
        #pragma unroll
        for (int j = 0; j < 8; ++j) {
            vf0[j] = Vw[(quad * 8 + j) * VSTRIDE + lo];
            vf1[j] = Vw[(quad * 8 + j) * VSTRIDE + 16 + lo];
        }
        o0 = __builtin_amdgcn_mfma_f32_16x16x32_bf16(pf, vf0, o0, 0, 0, 0);
        o1 = __builtin_amdgcn_mfma_f32_16x16x32_bf16(pf, vf1, o1, 0, 0, 0);
        __syncthreads();
    }

    float gw0 = gnw[h * HDIM + lo], gw1 = gnw[h * HDIM + 16 + lo];
    float gb0 = gnb[h * HDIM + lo], gb1 = gnb[h * HDIM + 16 + lo];
    bf16* QK = QKVG;
    #pragma unroll
    for (int r = 0; r < 4; ++r) {
        float y0 = o0[r], y1 = o1[r];
        float s = y0 + y1, ss = y0 * y0 + y1 * y1;
        #pragma unroll
        for (int off = 1; off < 16; off <<= 1) {
            s  += __shfl_xor(s, off);
            ss += __shfl_xor(ss, off);
        }
        float mu = s * (1.0f / HDIM);
        float var = ss * (1.0f / HDIM) - mu * mu;
        float rstd = rsqrtf(var + 1e-5f);
        int q = q0 + quad * 4 + r;
        size_t rowb = base + (size_t)q * 1024;
        float g0 = bf2f(QK[rowb + 768 + h * HDIM + lo]);
        float g1 = bf2f(QK[rowb + 768 + h * HDIM + 16 + lo]);
        float t0v = g0 / (1.0f + expf(-g0)) * ((y0 - mu) * rstd * gw0 + gb0);
        float t1v = g1 / (1.0f + expf(-g1)) * ((y1 - mu) * rstd * gw1 + gb1);
        QK[rowb + h * HDIM + lo]      = f2bf(t0v);
        QK[rowb + h * HDIM + 16 + lo] = f2bf(t1v);
    }
}

extern "C" void kernel_launch(void* const* d_in, const int* in_sizes, int n_in,
                              void* d_out, int out_size, void* d_ws, size_t ws_size,
                              hipStream_t stream) {
    const int*   v    = (const int*)d_in[0];
    const float* emb  = (const float*)d_in[1];
    const float* WQ   = (const float*)d_in[2];
    const float* WK   = (const float*)d_in[3];
    const float* WV   = (const float*)d_in[4];
    const float* WG   = (const float*)d_in[5];
    const float* WO   = (const float*)d_in[6];
    const float* gn_w = (const float*)d_in[7];
    const float* gn_b = (const float*)d_in[8];
    const float* ln1w = (const float*)d_in[9];
    const float* ln1b = (const float*)d_in[10];
    const float* ln2w = (const float*)d_in[11];
    const float* ln2b = (const float*)d_in[12];
    const float* w1   = (const float*)d_in[13];
    const float* b1   = (const float*)d_in[14];
    const float* w2   = (const float*)d_in[15];
    const float* b2   = (const float*)d_in[16];

    float* X = (float*)d_out;                    // residual stream (f32) in d_out

    float* base  = (float*)d_ws;
    int*   flag  = (int*)base;
    short* Xn    = (short*)(base + 16);          // NROWS*256 bf16
    bf16*  QKVG  = (bf16*)(Xn + (size_t)NROWS * 256);  // NROWS*1024
    bf16*  Hf    = QKVG + (size_t)NROWS * 1024;  // NROWS*128
    bf16*  WqkvgP = Hf + (size_t)NROWS * 128;    // 3*1024*256
    bf16*  WoP   = WqkvgP + 3 * 1024 * 256;      // 3*256*256
    bf16*  W1P   = WoP + 3 * 256 * 256;          // 3*128*256
    bf16*  W2P   = W1P + 3 * 128 * 256;          // 3*256*128
    float4* xpt  = (float4*)(W2P + 3 * 256 * 128); // 512*16 float4

    init_flag<<<1, 1, 0, stream>>>(flag);
    detect_v<<<32, 256, 0, stream>>>(v, flag);
    embed_kernel<<<NELEM / 256, 256, 0, stream>>>(v, emb, flag, X);
    xpos_table_kernel<<<32, 256, 0, stream>>>(xpt);
    pack_qkvg<<<3072, 256, 0, stream>>>(WQ, WK, WV, WG, WqkvgP);
    pack_wo<<<768, 256, 0, stream>>>(WO, WoP);
    pack_w1<<<384, 256, 0, stream>>>(w1, W1P);
    pack_w2<<<384, 256, 0, stream>>>(w2, W2P);

    for (int i = 0; i < 3; ++i) {
        // Xn = LN1(X) (bf16)
        ln_norm_kernel<<<NROWS, 256, 0, stream>>>(X, ln1w + i * DD, ln1b + i * DD, Xn);
        // QKVG = xpos(Xn @ [WQ|WK|WV|WG])  (bf16)
        mfma_gemm<4, 4, 0><<<dim3(8, 128), 256, 0, stream>>>(Xn, DD,
                                                             WqkvgP + (size_t)i * 1024 * 256,
                                                             nullptr, nullptr, 0, xpt, QKVG, 1024, 256);
        retention_mfma_kernel<<<2048, 256, 0, stream>>>(QKVG, gn_w + i * DD, gn_b + i * DD);
        // X += T @ WO
        mfma_gemm<2, 2, 1><<<dim3(4, 256), 256, 0, stream>>>((const short*)QKVG, 1024,
                                                             WoP + (size_t)i * 256 * 256,
                                                             nullptr, X, DD, nullptr, X, DD, 256);
        // Xn = LN2(X) (bf16)
        ln_norm_kernel<<<NROWS, 256, 0, stream>>>(X, ln2w + i * DD, ln2b + i * DD, Xn);
        // Hf = gelu(Xn @ w1 + b1)  (bf16)
        mfma_gemm<2, 2, 2><<<dim3(2, 256), 256, 0, stream>>>(Xn, DD,
                                                             W1P + (size_t)i * 128 * 256,
                                                             b1 + i * FFNN, nullptr, 0, nullptr, Hf, FFNN, 256);
        // X += Hf @ w2 + b2
        mfma_gemm<2, 2, 1><<<dim3(4, 256), 256, 0, stream>>>((const short*)Hf, FFNN,
                                                             W2P + (size_t)i * 256 * 128,
                                                             b2 + i * DD, X, DD, nullptr, X, DD, 128);
    }
}